// Round 1
// baseline (5177.596 us; speedup 1.0000x reference)
//
#include <hip/hip_runtime.h>
#include <hip/hip_bf16.h>

#define FCD 2048
#define VEMBD 512
#define WEMBD 512
#define HD 512
#define AD 256
#define TVD 32
#define TCD 20
#define BCD 16
#define RPD 32
#define BD 512     // BCD*RPD
#define GLOVED 300

__device__ __forceinline__ float sigf(float x) { return 1.0f / (1.0f + __expf(-x)); }
__device__ __forceinline__ float tanhfast(float x) {
    // tanh(x) = 1 - 2/(exp(2x)+1); saturates correctly for |x| large (no NaN)
    float e = __expf(2.0f * x);
    return 1.0f - 2.0f / (e + 1.0f);
}

// ---------------------------------------------------------------------------
// Generic fp32 tiled GEMM: C[M,N] = A[M,K] @ Bw[N,K]^T + bias[N]
// BM=BN=64, BK=16, 256 threads, 4x4 micro-tile. M,N must be multiples of 64.
// ---------------------------------------------------------------------------
__launch_bounds__(256)
__global__ void gemm_bias_kernel(const float* __restrict__ A,
                                 const float* __restrict__ Bw,
                                 const float* __restrict__ bias,
                                 float* __restrict__ C,
                                 int M, int N, int K) {
    __shared__ float As[16][68];
    __shared__ float Bs[16][68];
    const int n0 = blockIdx.x * 64;
    const int m0 = blockIdx.y * 64;
    const int tid = threadIdx.x;
    const int tx = tid & 15;
    const int ty = tid >> 4;
    const int lrow = tid >> 2;        // 0..63
    const int lk4 = (tid & 3) * 4;    // 0,4,8,12

    float acc[4][4] = {};

    for (int k0 = 0; k0 < K; k0 += 16) {
        // load A tile 64x16
        {
            const float* src = A + (long)(m0 + lrow) * K + k0 + lk4;
            float4 v;
            if (k0 + 16 <= K) {
                v = *(const float4*)src;
            } else {
                v.x = (k0 + lk4 + 0 < K) ? src[0] : 0.f;
                v.y = (k0 + lk4 + 1 < K) ? src[1] : 0.f;
                v.z = (k0 + lk4 + 2 < K) ? src[2] : 0.f;
                v.w = (k0 + lk4 + 3 < K) ? src[3] : 0.f;
            }
            As[lk4 + 0][lrow] = v.x; As[lk4 + 1][lrow] = v.y;
            As[lk4 + 2][lrow] = v.z; As[lk4 + 3][lrow] = v.w;
        }
        // load B tile 64x16
        {
            const float* src = Bw + (long)(n0 + lrow) * K + k0 + lk4;
            float4 v;
            if (k0 + 16 <= K) {
                v = *(const float4*)src;
            } else {
                v.x = (k0 + lk4 + 0 < K) ? src[0] : 0.f;
                v.y = (k0 + lk4 + 1 < K) ? src[1] : 0.f;
                v.z = (k0 + lk4 + 2 < K) ? src[2] : 0.f;
                v.w = (k0 + lk4 + 3 < K) ? src[3] : 0.f;
            }
            Bs[lk4 + 0][lrow] = v.x; Bs[lk4 + 1][lrow] = v.y;
            Bs[lk4 + 2][lrow] = v.z; Bs[lk4 + 3][lrow] = v.w;
        }
        __syncthreads();
#pragma unroll
        for (int kk = 0; kk < 16; kk++) {
            const float4 av = *(const float4*)&As[kk][ty * 4];
            const float4 bv = *(const float4*)&Bs[kk][tx * 4];
            acc[0][0] += av.x * bv.x; acc[0][1] += av.x * bv.y; acc[0][2] += av.x * bv.z; acc[0][3] += av.x * bv.w;
            acc[1][0] += av.y * bv.x; acc[1][1] += av.y * bv.y; acc[1][2] += av.y * bv.z; acc[1][3] += av.y * bv.w;
            acc[2][0] += av.z * bv.x; acc[2][1] += av.z * bv.y; acc[2][2] += av.z * bv.z; acc[2][3] += av.z * bv.w;
            acc[3][0] += av.w * bv.x; acc[3][1] += av.w * bv.y; acc[3][2] += av.w * bv.z; acc[3][3] += av.w * bv.w;
        }
        __syncthreads();
    }

    const float b0 = bias[n0 + tx * 4 + 0];
    const float b1 = bias[n0 + tx * 4 + 1];
    const float b2 = bias[n0 + tx * 4 + 2];
    const float b3 = bias[n0 + tx * 4 + 3];
#pragma unroll
    for (int i = 0; i < 4; i++) {
        float* dst = C + (long)(m0 + ty * 4 + i) * N + n0 + tx * 4;
        dst[0] = acc[i][0] + b0;
        dst[1] = acc[i][1] + b1;
        dst[2] = acc[i][2] + b2;
        dst[3] = acc[i][3] + b3;
    }
}

// ---------------------------------------------------------------------------
// Caption LSTM: 16 blocks (one per caption batch), 512 threads (one per h idx).
// xg = cap_x @ Wih_c^T + bih_c  (precomputed).  Adds bhh + h@Whh^T per step.
// ---------------------------------------------------------------------------
__launch_bounds__(512)
__global__ void cap_lstm_kernel(const float* __restrict__ xg,    // [BC*TC][2048]
                                const float* __restrict__ Whh,   // [2048][512]
                                const float* __restrict__ bhh,   // [2048]
                                float* __restrict__ cap_h)       // [BC*TC][512]
{
    const int b = blockIdx.x;
    const int j = threadIdx.x;
    __shared__ float hl[HD];
    float c = 0.f;
    hl[j] = 0.f;
    const float bh0 = bhh[j], bh1 = bhh[512 + j], bh2 = bhh[1024 + j], bh3 = bhh[1536 + j];
    const float* w0 = Whh + (long)j * HD;
    const float* w1 = Whh + (long)(512 + j) * HD;
    const float* w2 = Whh + (long)(1024 + j) * HD;
    const float* w3 = Whh + (long)(1536 + j) * HD;
    __syncthreads();
    for (int t = 0; t < TCD; t++) {
        const float* xr = xg + (long)(b * TCD + t) * 2048;
        float gi = xr[j] + bh0;
        float gf = xr[512 + j] + bh1;
        float gg = xr[1024 + j] + bh2;
        float go = xr[1536 + j] + bh3;
#pragma unroll 4
        for (int k = 0; k < HD; k += 4) {
            const float4 h4 = *(const float4*)&hl[k];
            const float4 a0 = *(const float4*)&w0[k];
            const float4 a1 = *(const float4*)&w1[k];
            const float4 a2 = *(const float4*)&w2[k];
            const float4 a3 = *(const float4*)&w3[k];
            gi += h4.x * a0.x + h4.y * a0.y + h4.z * a0.z + h4.w * a0.w;
            gf += h4.x * a1.x + h4.y * a1.y + h4.z * a1.z + h4.w * a1.w;
            gg += h4.x * a2.x + h4.y * a2.y + h4.z * a2.z + h4.w * a2.w;
            go += h4.x * a3.x + h4.y * a3.y + h4.z * a3.z + h4.w * a3.w;
        }
        const float ii = sigf(gi), ff = sigf(gf), g2 = tanhfast(gg), oo = sigf(go);
        c = ff * c + ii * g2;
        const float h = oo * tanhfast(c);
        __syncthreads();
        hl[j] = h;
        cap_h[(long)(b * TCD + t) * HD + j] = h;
        __syncthreads();
    }
}

// ---------------------------------------------------------------------------
// Video LSTM step t: gates[b][q*512+hc] = [vid_x[b,t,:], h_in[b,:]] (K=1024)
//   dot [Wih_v ; Whh_v] rows, + biases, then cell update.
// Tiles: 64 batch x 16 h-cols (=> 64 gate cols). 512 threads, acc[2][4].
// Grid (32, 8) = 256 blocks.
// ---------------------------------------------------------------------------
__launch_bounds__(512)
__global__ void vid_step_kernel(const float* __restrict__ vx,    // [B*TV][512]
                                const float* __restrict__ Wih,   // [2048][512]
                                const float* __restrict__ Whh,   // [2048][512]
                                const float* __restrict__ bih,
                                const float* __restrict__ bhh,
                                const float* __restrict__ h_in,  // [512][512]
                                float* __restrict__ h_out,
                                float* __restrict__ c_state,
                                float* __restrict__ vid_h,       // [B*TV][512]
                                int t)
{
    __shared__ float As[32][68];   // [BK][64 batch + pad]
    __shared__ float Ws[32][68];   // [BK][hc*4+q + pad]
    const int h0 = blockIdx.x * 16;
    const int b0 = blockIdx.y * 64;
    const int tid = threadIdx.x;
    const int tx = tid & 15;       // h col in tile
    const int ty = tid >> 4;       // 0..31 -> 2 batch rows each
    const int lrow = tid >> 3;     // 0..63 (loader)
    const int lk4 = (tid & 7) * 4; // 0..28 (loader)

    float acc[2][4] = {};

    for (int k0 = 0; k0 < 1024; k0 += 32) {
        // A tile: batch rows
        {
            const int b = b0 + lrow;
            const int k = k0 + lk4;
            const float* src = (k < 512) ? (vx + ((long)b * TVD + t) * 512 + k)
                                         : (h_in + (long)b * 512 + (k - 512));
            const float4 v = *(const float4*)src;
            As[lk4 + 0][lrow] = v.x; As[lk4 + 1][lrow] = v.y;
            As[lk4 + 2][lrow] = v.z; As[lk4 + 3][lrow] = v.w;
        }
        // W tile: 64 rows = (q in 0..3) x (hc in 0..15); LDS col = hc*4+q
        {
            const int q = lrow >> 4;
            const int hc = lrow & 15;
            const long grow = (long)(q * 512 + h0 + hc);
            const int k = k0 + lk4;
            const float* src = (k < 512) ? (Wih + grow * 512 + k)
                                         : (Whh + grow * 512 + (k - 512));
            const float4 v = *(const float4*)src;
            const int col = hc * 4 + q;
            Ws[lk4 + 0][col] = v.x; Ws[lk4 + 1][col] = v.y;
            Ws[lk4 + 2][col] = v.z; Ws[lk4 + 3][col] = v.w;
        }
        __syncthreads();
#pragma unroll
        for (int kk = 0; kk < 32; kk++) {
            const float a0 = As[kk][ty * 2 + 0];
            const float a1 = As[kk][ty * 2 + 1];
            const float4 wv = *(const float4*)&Ws[kk][tx * 4];
            acc[0][0] += a0 * wv.x; acc[0][1] += a0 * wv.y; acc[0][2] += a0 * wv.z; acc[0][3] += a0 * wv.w;
            acc[1][0] += a1 * wv.x; acc[1][1] += a1 * wv.y; acc[1][2] += a1 * wv.z; acc[1][3] += a1 * wv.w;
        }
        __syncthreads();
    }

    const int hc = h0 + tx;
    const float bi0 = bih[hc] + bhh[hc];
    const float bi1 = bih[512 + hc] + bhh[512 + hc];
    const float bi2 = bih[1024 + hc] + bhh[1024 + hc];
    const float bi3 = bih[1536 + hc] + bhh[1536 + hc];
#pragma unroll
    for (int i = 0; i < 2; i++) {
        const int b = b0 + ty * 2 + i;
        const float gi = acc[i][0] + bi0;
        const float gf = acc[i][1] + bi1;
        const float gg = acc[i][2] + bi2;
        const float go = acc[i][3] + bi3;
        const float c_old = c_state[(long)b * 512 + hc];
        const float ii = sigf(gi), ff = sigf(gf), g2 = tanhfast(gg), oo = sigf(go);
        const float c = ff * c_old + ii * g2;
        const float h = oo * tanhfast(c);
        c_state[(long)b * 512 + hc] = c;
        h_out[(long)b * 512 + hc] = h;
        vid_h[((long)b * TVD + t) * 512 + hc] = h;
    }
}

// ---------------------------------------------------------------------------
// Attention: one block per (bc, rp). Computes scores (32 v x 20 t), masked
// softmax over t, then wbar[br][t] = mean_v w.
// ---------------------------------------------------------------------------
__launch_bounds__(256)
__global__ void attn_kernel(const float* __restrict__ v_lin,  // [B*TV][256]
                            const float* __restrict__ c_lin,  // [BC*TC][256]
                            const float* __restrict__ W_att,  // [256]
                            const float* __restrict__ b_att,  // [1]
                            const int* __restrict__ cap_len,  // [BC]
                            float* __restrict__ wbar)         // [B][20]
{
    const int br = blockIdx.x;      // 0..511
    const int bc = br >> 5;
    const int tid = threadIdx.x;
    const int lane = tid & 63;
    const int wv = tid >> 6;        // wave 0..3 -> t in [wv*5, wv*5+5)
    __shared__ float cl[TCD][AD];
    __shared__ float vl[AD];
    __shared__ float sl[TVD][TCD];

    for (int tt = 0; tt < TCD; tt++)
        cl[tt][tid] = c_lin[(long)(bc * TCD + tt) * AD + tid];
    const float wa0 = W_att[lane];
    const float wa1 = W_att[64 + lane];
    const float wa2 = W_att[128 + lane];
    const float wa3 = W_att[192 + lane];
    const float batt = b_att[0];
    __syncthreads();

    for (int v = 0; v < TVD; v++) {
        vl[tid] = v_lin[((long)br * TVD + v) * AD + tid];
        __syncthreads();
        const float v0 = vl[lane], v1 = vl[64 + lane], v2 = vl[128 + lane], v3 = vl[192 + lane];
#pragma unroll
        for (int dt = 0; dt < 5; dt++) {
            const int t = wv * 5 + dt;
            float s = tanhfast(v0 + cl[t][lane]) * wa0
                    + tanhfast(v1 + cl[t][64 + lane]) * wa1
                    + tanhfast(v2 + cl[t][128 + lane]) * wa2
                    + tanhfast(v3 + cl[t][192 + lane]) * wa3;
            for (int off = 32; off > 0; off >>= 1) s += __shfl_down(s, off, 64);
            if (lane == 0) sl[v][t] = s + batt;
        }
        __syncthreads();
    }

    int L = cap_len[bc];
    if (L < 1) L = 1;
    if (tid < TVD) {
        const int v = tid;
        float m = -1e30f;
        for (int t = 0; t < TCD; t++)
            if (t < L) m = fmaxf(m, sl[v][t]);
        float sum = 0.f;
        for (int t = 0; t < TCD; t++)
            if (t < L) sum += __expf(sl[v][t] - m);
        const float inv = 1.f / sum;
        for (int t = 0; t < TCD; t++)
            sl[v][t] = (t < L) ? __expf(sl[v][t] - m) * inv : 0.f;
    }
    __syncthreads();
    if (tid < TCD) {
        float s = 0.f;
        for (int v = 0; v < TVD; v++) s += sl[v][tid];
        wbar[(long)br * TCD + tid] = s * (1.0f / TVD);
    }
}

// cap_ftr_mean[br][h] = sum_t wbar[br][t] * cap_h[bc][t][h]
__launch_bounds__(256)
__global__ void capftr_kernel(const float* __restrict__ wbar,
                              const float* __restrict__ cap_h,
                              float* __restrict__ out2)
{
    const int idx = blockIdx.x * 256 + threadIdx.x;   // 0..262143
    const int h = idx & 511;
    const int br = idx >> 9;
    const int bc = br >> 5;
    float s = 0.f;
#pragma unroll
    for (int t = 0; t < TCD; t++)
        s += wbar[br * TCD + t] * cap_h[(long)(bc * TCD + t) * HD + h];
    out2[idx] = s;
}

// vid_mean[b][h] = mean_t vid_h[b][t][h]
__launch_bounds__(256)
__global__ void vidmean_kernel(const float* __restrict__ vid_h,
                               float* __restrict__ out1)
{
    const int idx = blockIdx.x * 256 + threadIdx.x;   // 0..262143
    const int h = idx & 511;
    const int b = idx >> 9;
    float s = 0.f;
#pragma unroll
    for (int t = 0; t < TVD; t++)
        s += vid_h[((long)b * TVD + t) * HD + h];
    out1[idx] = s * (1.0f / TVD);
}

extern "C" void kernel_launch(void* const* d_in, const int* in_sizes, int n_in,
                              void* d_out, int out_size, void* d_ws, size_t ws_size,
                              hipStream_t stream) {
    const float* video_fc      = (const float*)d_in[0];
    const float* video_caption = (const float*)d_in[1];
    const int*   cap_len       = (const int*)d_in[2];
    const float* W_vemb = (const float*)d_in[3];
    const float* b_vemb = (const float*)d_in[4];
    const float* W_wemb = (const float*)d_in[5];
    const float* b_wemb = (const float*)d_in[6];
    const float* Wih_v  = (const float*)d_in[7];
    const float* Whh_v  = (const float*)d_in[8];
    const float* bih_v  = (const float*)d_in[9];
    const float* bhh_v  = (const float*)d_in[10];
    const float* Wih_c  = (const float*)d_in[11];
    const float* Whh_c  = (const float*)d_in[12];
    const float* bih_c  = (const float*)d_in[13];
    const float* bhh_c  = (const float*)d_in[14];
    const float* W_vid  = (const float*)d_in[15];
    const float* b_vid  = (const float*)d_in[16];
    const float* W_sen  = (const float*)d_in[17];
    const float* b_sen  = (const float*)d_in[18];
    const float* W_att  = (const float*)d_in[19];
    const float* b_att  = (const float*)d_in[20];

    float* out1 = (float*)d_out;            // vid_mean   (16*32*512)
    float* out2 = out1 + BD * HD;           // cap_ftr    (16*32*512)

    float* ws = (float*)d_ws;
    size_t off = 0;
    float* vid_x = ws + off; off += (size_t)BD * TVD * VEMBD;   // 8.39M
    float* vid_h = ws + off; off += (size_t)BD * TVD * HD;      // 8.39M
    float* h_a   = ws + off; off += (size_t)BD * HD;
    float* h_b   = ws + off; off += (size_t)BD * HD;
    float* c_st  = ws + off; off += (size_t)BD * HD;
    float* cap_x = ws + off; off += (size_t)BCD * TCD * WEMBD;
    float* xg_c  = ws + off; off += (size_t)BCD * TCD * 4 * HD;
    float* cap_h = ws + off; off += (size_t)BCD * TCD * HD;
    float* c_lin = ws + off; off += (size_t)BCD * TCD * AD;
    float* v_lin = ws + off; off += (size_t)BD * TVD * AD;      // 4.19M
    float* wbar  = ws + off; off += (size_t)BD * TCD;

    hipMemsetAsync(h_a, 0, (size_t)BD * HD * sizeof(float), stream);
    hipMemsetAsync(c_st, 0, (size_t)BD * HD * sizeof(float), stream);

    // caption path
    gemm_bias_kernel<<<dim3(WEMBD / 64, (BCD * TCD) / 64), 256, 0, stream>>>(
        video_caption, W_wemb, b_wemb, cap_x, BCD * TCD, WEMBD, GLOVED);
    gemm_bias_kernel<<<dim3((4 * HD) / 64, (BCD * TCD) / 64), 256, 0, stream>>>(
        cap_x, Wih_c, bih_c, xg_c, BCD * TCD, 4 * HD, WEMBD);
    cap_lstm_kernel<<<BCD, 512, 0, stream>>>(xg_c, Whh_c, bhh_c, cap_h);
    gemm_bias_kernel<<<dim3(AD / 64, (BCD * TCD) / 64), 256, 0, stream>>>(
        cap_h, W_sen, b_sen, c_lin, BCD * TCD, AD, HD);

    // video path
    gemm_bias_kernel<<<dim3(VEMBD / 64, (BD * TVD) / 64), 256, 0, stream>>>(
        video_fc, W_vemb, b_vemb, vid_x, BD * TVD, VEMBD, FCD);
    for (int t = 0; t < TVD; t++) {
        const float* hin = (t & 1) ? h_b : h_a;
        float* hout = (t & 1) ? h_a : h_b;
        vid_step_kernel<<<dim3(HD / 16, BD / 64), 512, 0, stream>>>(
            vid_x, Wih_v, Whh_v, bih_v, bhh_v, hin, hout, c_st, vid_h, t);
    }
    gemm_bias_kernel<<<dim3(AD / 64, (BD * TVD) / 64), 256, 0, stream>>>(
        vid_h, W_vid, b_vid, v_lin, BD * TVD, AD, HD);

    // attention + outputs
    attn_kernel<<<BD, 256, 0, stream>>>(v_lin, c_lin, W_att, b_att, cap_len, wbar);
    capftr_kernel<<<(BD * HD) / 256, 256, 0, stream>>>(wbar, cap_h, out2);
    vidmean_kernel<<<(BD * HD) / 256, 256, 0, stream>>>(vid_h, out1);
}

// Round 2
// 2940.568 us; speedup vs baseline: 1.7607x; 1.7607x over previous
//
#include <hip/hip_runtime.h>
#include <hip/hip_bf16.h>

#define FCD 2048
#define VEMBD 512
#define WEMBD 512
#define HD 512
#define AD 256
#define TVD 32
#define TCD 20
#define BCD 16
#define RPD 32
#define BD 512     // BCD*RPD
#define GLOVED 300

__device__ __forceinline__ float sigf(float x) { return 1.0f / (1.0f + __expf(-x)); }
__device__ __forceinline__ float tanhfast(float x) {
    // tanh(x) = 1 - 2/(exp(2x)+1); saturates correctly for |x| large (no NaN)
    float e = __expf(2.0f * x);
    return 1.0f - 2.0f / (e + 1.0f);
}

// ---------------------------------------------------------------------------
// Generic fp32 tiled GEMM: C[M,N] = A[M,K] @ Bw[N,K]^T + bias[N]
// BM=BN=64, BK=16, 256 threads, 4x4 micro-tile. M,N must be multiples of 64.
// ---------------------------------------------------------------------------
__launch_bounds__(256)
__global__ void gemm_bias_kernel(const float* __restrict__ A,
                                 const float* __restrict__ Bw,
                                 const float* __restrict__ bias,
                                 float* __restrict__ C,
                                 int M, int N, int K) {
    __shared__ float As[16][68];
    __shared__ float Bs[16][68];
    const int n0 = blockIdx.x * 64;
    const int m0 = blockIdx.y * 64;
    const int tid = threadIdx.x;
    const int tx = tid & 15;
    const int ty = tid >> 4;
    const int lrow = tid >> 2;        // 0..63
    const int lk4 = (tid & 3) * 4;    // 0,4,8,12

    float acc[4][4] = {};

    for (int k0 = 0; k0 < K; k0 += 16) {
        // load A tile 64x16
        {
            const float* src = A + (long)(m0 + lrow) * K + k0 + lk4;
            float4 v;
            if (k0 + 16 <= K) {
                v = *(const float4*)src;
            } else {
                v.x = (k0 + lk4 + 0 < K) ? src[0] : 0.f;
                v.y = (k0 + lk4 + 1 < K) ? src[1] : 0.f;
                v.z = (k0 + lk4 + 2 < K) ? src[2] : 0.f;
                v.w = (k0 + lk4 + 3 < K) ? src[3] : 0.f;
            }
            As[lk4 + 0][lrow] = v.x; As[lk4 + 1][lrow] = v.y;
            As[lk4 + 2][lrow] = v.z; As[lk4 + 3][lrow] = v.w;
        }
        // load B tile 64x16
        {
            const float* src = Bw + (long)(n0 + lrow) * K + k0 + lk4;
            float4 v;
            if (k0 + 16 <= K) {
                v = *(const float4*)src;
            } else {
                v.x = (k0 + lk4 + 0 < K) ? src[0] : 0.f;
                v.y = (k0 + lk4 + 1 < K) ? src[1] : 0.f;
                v.z = (k0 + lk4 + 2 < K) ? src[2] : 0.f;
                v.w = (k0 + lk4 + 3 < K) ? src[3] : 0.f;
            }
            Bs[lk4 + 0][lrow] = v.x; Bs[lk4 + 1][lrow] = v.y;
            Bs[lk4 + 2][lrow] = v.z; Bs[lk4 + 3][lrow] = v.w;
        }
        __syncthreads();
#pragma unroll
        for (int kk = 0; kk < 16; kk++) {
            const float4 av = *(const float4*)&As[kk][ty * 4];
            const float4 bv = *(const float4*)&Bs[kk][tx * 4];
            acc[0][0] += av.x * bv.x; acc[0][1] += av.x * bv.y; acc[0][2] += av.x * bv.z; acc[0][3] += av.x * bv.w;
            acc[1][0] += av.y * bv.x; acc[1][1] += av.y * bv.y; acc[1][2] += av.y * bv.z; acc[1][3] += av.y * bv.w;
            acc[2][0] += av.z * bv.x; acc[2][1] += av.z * bv.y; acc[2][2] += av.z * bv.z; acc[2][3] += av.z * bv.w;
            acc[3][0] += av.w * bv.x; acc[3][1] += av.w * bv.y; acc[3][2] += av.w * bv.z; acc[3][3] += av.w * bv.w;
        }
        __syncthreads();
    }

    const float b0 = bias[n0 + tx * 4 + 0];
    const float b1 = bias[n0 + tx * 4 + 1];
    const float b2 = bias[n0 + tx * 4 + 2];
    const float b3 = bias[n0 + tx * 4 + 3];
#pragma unroll
    for (int i = 0; i < 4; i++) {
        float* dst = C + (long)(m0 + ty * 4 + i) * N + n0 + tx * 4;
        dst[0] = acc[i][0] + b0;
        dst[1] = acc[i][1] + b1;
        dst[2] = acc[i][2] + b2;
        dst[3] = acc[i][3] + b3;
    }
}

// ---------------------------------------------------------------------------
// Caption LSTM step t (replaces the 16-block persistent kernel, which was
// latency-bound: 1.5% occupancy, 0.5% VALUBusy, 2.4 ms).
// Grid: 32 blocks x 256 threads. Block = 16 h-cols x 16 batches x 4 gates.
// gates = xg[b,t,:] (x@Wih+bih precomputed) + bhh + h_in @ Whh^T, then cell.
// LDS: Whh tile 64 gate-rows x 64 k (16KB), h tile 16 x 64 (4KB).
// ---------------------------------------------------------------------------
__launch_bounds__(256)
__global__ void cap_step_kernel(const float* __restrict__ xg,   // [BC*TC][2048]
                                const float* __restrict__ Whh,  // [2048][512]
                                const float* __restrict__ bhh,  // [2048]
                                const float* __restrict__ h_in, // [BC][512]
                                float* __restrict__ h_out,      // [BC][512]
                                float* __restrict__ c_state,    // [BC][512]
                                float* __restrict__ cap_h,      // [BC*TC][512]
                                int t)
{
    __shared__ float Ws[64][68];   // [k][hcc*4+q]
    __shared__ float Hs[16][68];   // [b][k]
    const int h0 = blockIdx.x * 16;
    const int tid = threadIdx.x;
    const int tx = tid & 15;    // h col in tile
    const int ty = tid >> 4;    // batch 0..15
    const int lrow = tid >> 2;  // 0..63 (W loader row)
    const int lq = tid & 3;     // k-quarter

    float acc[4] = {};

    for (int k0 = 0; k0 < 512; k0 += 64) {
        // W tile: 64 rows = (q in 0..3) x (hcc in 0..15), k chunk of 64
        {
            const int q = lrow >> 4;
            const int hcc = lrow & 15;
            const float* src = Whh + (long)(q * 512 + h0 + hcc) * 512 + k0 + lq * 16;
            const int col = hcc * 4 + q;
#pragma unroll
            for (int j = 0; j < 4; j++) {
                const float4 v = *(const float4*)(src + j * 4);
                Ws[lq * 16 + j * 4 + 0][col] = v.x;
                Ws[lq * 16 + j * 4 + 1][col] = v.y;
                Ws[lq * 16 + j * 4 + 2][col] = v.z;
                Ws[lq * 16 + j * 4 + 3][col] = v.w;
            }
        }
        // H tile: Hs[b][kk]
        {
            const int lb = tid >> 4;
            const int lk4 = (tid & 15) * 4;
            *(float4*)&Hs[lb][lk4] = *(const float4*)(h_in + (long)lb * 512 + k0 + lk4);
        }
        __syncthreads();
#pragma unroll
        for (int kq = 0; kq < 16; kq++) {
            const float4 h4 = *(const float4*)&Hs[ty][kq * 4];
            const float4 w0 = *(const float4*)&Ws[kq * 4 + 0][tx * 4];
            const float4 w1 = *(const float4*)&Ws[kq * 4 + 1][tx * 4];
            const float4 w2 = *(const float4*)&Ws[kq * 4 + 2][tx * 4];
            const float4 w3 = *(const float4*)&Ws[kq * 4 + 3][tx * 4];
            acc[0] += h4.x * w0.x + h4.y * w1.x + h4.z * w2.x + h4.w * w3.x;
            acc[1] += h4.x * w0.y + h4.y * w1.y + h4.z * w2.y + h4.w * w3.y;
            acc[2] += h4.x * w0.z + h4.y * w1.z + h4.z * w2.z + h4.w * w3.z;
            acc[3] += h4.x * w0.w + h4.y * w1.w + h4.z * w2.w + h4.w * w3.w;
        }
        __syncthreads();
    }

    const int hc = h0 + tx;
    const long xrow = (long)(ty * TCD + t) * 2048;
    const float gi = acc[0] + xg[xrow + hc]        + bhh[hc];
    const float gf = acc[1] + xg[xrow + 512 + hc]  + bhh[512 + hc];
    const float gg = acc[2] + xg[xrow + 1024 + hc] + bhh[1024 + hc];
    const float go = acc[3] + xg[xrow + 1536 + hc] + bhh[1536 + hc];
    const float c_old = c_state[(long)ty * 512 + hc];
    const float ii = sigf(gi), ff = sigf(gf), g2 = tanhfast(gg), oo = sigf(go);
    const float c = ff * c_old + ii * g2;
    const float h = oo * tanhfast(c);
    c_state[(long)ty * 512 + hc] = c;
    h_out[(long)ty * 512 + hc] = h;
    cap_h[(long)(ty * TCD + t) * 512 + hc] = h;
}

// ---------------------------------------------------------------------------
// Video LSTM step t: gates[b][q*512+hc] = [vid_x[b,t,:], h_in[b,:]] (K=1024)
//   dot [Wih_v ; Whh_v] rows, + biases, then cell update.
// Tiles: 64 batch x 16 h-cols (=> 64 gate cols). 512 threads, acc[2][4].
// Grid (32, 8) = 256 blocks.
// ---------------------------------------------------------------------------
__launch_bounds__(512)
__global__ void vid_step_kernel(const float* __restrict__ vx,    // [B*TV][512]
                                const float* __restrict__ Wih,   // [2048][512]
                                const float* __restrict__ Whh,   // [2048][512]
                                const float* __restrict__ bih,
                                const float* __restrict__ bhh,
                                const float* __restrict__ h_in,  // [512][512]
                                float* __restrict__ h_out,
                                float* __restrict__ c_state,
                                float* __restrict__ vid_h,       // [B*TV][512]
                                int t)
{
    __shared__ float As[32][68];   // [BK][64 batch + pad]
    __shared__ float Ws[32][68];   // [BK][hc*4+q + pad]
    const int h0 = blockIdx.x * 16;
    const int b0 = blockIdx.y * 64;
    const int tid = threadIdx.x;
    const int tx = tid & 15;       // h col in tile
    const int ty = tid >> 4;       // 0..31 -> 2 batch rows each
    const int lrow = tid >> 3;     // 0..63 (loader)
    const int lk4 = (tid & 7) * 4; // 0..28 (loader)

    float acc[2][4] = {};

    for (int k0 = 0; k0 < 1024; k0 += 32) {
        // A tile: batch rows
        {
            const int b = b0 + lrow;
            const int k = k0 + lk4;
            const float* src = (k < 512) ? (vx + ((long)b * TVD + t) * 512 + k)
                                         : (h_in + (long)b * 512 + (k - 512));
            const float4 v = *(const float4*)src;
            As[lk4 + 0][lrow] = v.x; As[lk4 + 1][lrow] = v.y;
            As[lk4 + 2][lrow] = v.z; As[lk4 + 3][lrow] = v.w;
        }
        // W tile: 64 rows = (q in 0..3) x (hc in 0..15); LDS col = hc*4+q
        {
            const int q = lrow >> 4;
            const int hc = lrow & 15;
            const long grow = (long)(q * 512 + h0 + hc);
            const int k = k0 + lk4;
            const float* src = (k < 512) ? (Wih + grow * 512 + k)
                                         : (Whh + grow * 512 + (k - 512));
            const float4 v = *(const float4*)src;
            const int col = hc * 4 + q;
            Ws[lk4 + 0][col] = v.x; Ws[lk4 + 1][col] = v.y;
            Ws[lk4 + 2][col] = v.z; Ws[lk4 + 3][col] = v.w;
        }
        __syncthreads();
#pragma unroll
        for (int kk = 0; kk < 32; kk++) {
            const float a0 = As[kk][ty * 2 + 0];
            const float a1 = As[kk][ty * 2 + 1];
            const float4 wv = *(const float4*)&Ws[kk][tx * 4];
            acc[0][0] += a0 * wv.x; acc[0][1] += a0 * wv.y; acc[0][2] += a0 * wv.z; acc[0][3] += a0 * wv.w;
            acc[1][0] += a1 * wv.x; acc[1][1] += a1 * wv.y; acc[1][2] += a1 * wv.z; acc[1][3] += a1 * wv.w;
        }
        __syncthreads();
    }

    const int hc = h0 + tx;
    const float bi0 = bih[hc] + bhh[hc];
    const float bi1 = bih[512 + hc] + bhh[512 + hc];
    const float bi2 = bih[1024 + hc] + bhh[1024 + hc];
    const float bi3 = bih[1536 + hc] + bhh[1536 + hc];
#pragma unroll
    for (int i = 0; i < 2; i++) {
        const int b = b0 + ty * 2 + i;
        const float gi = acc[i][0] + bi0;
        const float gf = acc[i][1] + bi1;
        const float gg = acc[i][2] + bi2;
        const float go = acc[i][3] + bi3;
        const float c_old = c_state[(long)b * 512 + hc];
        const float ii = sigf(gi), ff = sigf(gf), g2 = tanhfast(gg), oo = sigf(go);
        const float c = ff * c_old + ii * g2;
        const float h = oo * tanhfast(c);
        c_state[(long)b * 512 + hc] = c;
        h_out[(long)b * 512 + hc] = h;
        vid_h[((long)b * TVD + t) * 512 + hc] = h;
    }
}

// ---------------------------------------------------------------------------
// Attention: one block per (bc, rp). Computes scores (32 v x 20 t), masked
// softmax over t, then wbar[br][t] = mean_v w.
// ---------------------------------------------------------------------------
__launch_bounds__(256)
__global__ void attn_kernel(const float* __restrict__ v_lin,  // [B*TV][256]
                            const float* __restrict__ c_lin,  // [BC*TC][256]
                            const float* __restrict__ W_att,  // [256]
                            const float* __restrict__ b_att,  // [1]
                            const int* __restrict__ cap_len,  // [BC]
                            float* __restrict__ wbar)         // [B][20]
{
    const int br = blockIdx.x;      // 0..511
    const int bc = br >> 5;
    const int tid = threadIdx.x;
    const int lane = tid & 63;
    const int wv = tid >> 6;        // wave 0..3 -> t in [wv*5, wv*5+5)
    __shared__ float cl[TCD][AD];
    __shared__ float vl[AD];
    __shared__ float sl[TVD][TCD];

    for (int tt = 0; tt < TCD; tt++)
        cl[tt][tid] = c_lin[(long)(bc * TCD + tt) * AD + tid];
    const float wa0 = W_att[lane];
    const float wa1 = W_att[64 + lane];
    const float wa2 = W_att[128 + lane];
    const float wa3 = W_att[192 + lane];
    const float batt = b_att[0];
    __syncthreads();

    for (int v = 0; v < TVD; v++) {
        vl[tid] = v_lin[((long)br * TVD + v) * AD + tid];
        __syncthreads();
        const float v0 = vl[lane], v1 = vl[64 + lane], v2 = vl[128 + lane], v3 = vl[192 + lane];
#pragma unroll
        for (int dt = 0; dt < 5; dt++) {
            const int t = wv * 5 + dt;
            float s = tanhfast(v0 + cl[t][lane]) * wa0
                    + tanhfast(v1 + cl[t][64 + lane]) * wa1
                    + tanhfast(v2 + cl[t][128 + lane]) * wa2
                    + tanhfast(v3 + cl[t][192 + lane]) * wa3;
            for (int off = 32; off > 0; off >>= 1) s += __shfl_down(s, off, 64);
            if (lane == 0) sl[v][t] = s + batt;
        }
        __syncthreads();
    }

    int L = cap_len[bc];
    if (L < 1) L = 1;
    if (tid < TVD) {
        const int v = tid;
        float m = -1e30f;
        for (int t = 0; t < TCD; t++)
            if (t < L) m = fmaxf(m, sl[v][t]);
        float sum = 0.f;
        for (int t = 0; t < TCD; t++)
            if (t < L) sum += __expf(sl[v][t] - m);
        const float inv = 1.f / sum;
        for (int t = 0; t < TCD; t++)
            sl[v][t] = (t < L) ? __expf(sl[v][t] - m) * inv : 0.f;
    }
    __syncthreads();
    if (tid < TCD) {
        float s = 0.f;
        for (int v = 0; v < TVD; v++) s += sl[v][tid];
        wbar[(long)br * TCD + tid] = s * (1.0f / TVD);
    }
}

// cap_ftr_mean[br][h] = sum_t wbar[br][t] * cap_h[bc][t][h]
__launch_bounds__(256)
__global__ void capftr_kernel(const float* __restrict__ wbar,
                              const float* __restrict__ cap_h,
                              float* __restrict__ out2)
{
    const int idx = blockIdx.x * 256 + threadIdx.x;   // 0..262143
    const int h = idx & 511;
    const int br = idx >> 9;
    const int bc = br >> 5;
    float s = 0.f;
#pragma unroll
    for (int t = 0; t < TCD; t++)
        s += wbar[br * TCD + t] * cap_h[(long)(bc * TCD + t) * HD + h];
    out2[idx] = s;
}

// vid_mean[b][h] = mean_t vid_h[b][t][h]
__launch_bounds__(256)
__global__ void vidmean_kernel(const float* __restrict__ vid_h,
                               float* __restrict__ out1)
{
    const int idx = blockIdx.x * 256 + threadIdx.x;   // 0..262143
    const int h = idx & 511;
    const int b = idx >> 9;
    float s = 0.f;
#pragma unroll
    for (int t = 0; t < TVD; t++)
        s += vid_h[((long)b * TVD + t) * HD + h];
    out1[idx] = s * (1.0f / TVD);
}

extern "C" void kernel_launch(void* const* d_in, const int* in_sizes, int n_in,
                              void* d_out, int out_size, void* d_ws, size_t ws_size,
                              hipStream_t stream) {
    const float* video_fc      = (const float*)d_in[0];
    const float* video_caption = (const float*)d_in[1];
    const int*   cap_len       = (const int*)d_in[2];
    const float* W_vemb = (const float*)d_in[3];
    const float* b_vemb = (const float*)d_in[4];
    const float* W_wemb = (const float*)d_in[5];
    const float* b_wemb = (const float*)d_in[6];
    const float* Wih_v  = (const float*)d_in[7];
    const float* Whh_v  = (const float*)d_in[8];
    const float* bih_v  = (const float*)d_in[9];
    const float* bhh_v  = (const float*)d_in[10];
    const float* Wih_c  = (const float*)d_in[11];
    const float* Whh_c  = (const float*)d_in[12];
    const float* bih_c  = (const float*)d_in[13];
    const float* bhh_c  = (const float*)d_in[14];
    const float* W_vid  = (const float*)d_in[15];
    const float* b_vid  = (const float*)d_in[16];
    const float* W_sen  = (const float*)d_in[17];
    const float* b_sen  = (const float*)d_in[18];
    const float* W_att  = (const float*)d_in[19];
    const float* b_att  = (const float*)d_in[20];

    float* out1 = (float*)d_out;            // vid_mean   (16*32*512)
    float* out2 = out1 + BD * HD;           // cap_ftr    (16*32*512)

    float* ws = (float*)d_ws;
    size_t off = 0;
    float* vid_x = ws + off; off += (size_t)BD * TVD * VEMBD;   // 8.39M
    float* vid_h = ws + off; off += (size_t)BD * TVD * HD;      // 8.39M
    float* h_a   = ws + off; off += (size_t)BD * HD;
    float* h_b   = ws + off; off += (size_t)BD * HD;
    float* c_st  = ws + off; off += (size_t)BD * HD;
    float* cap_x = ws + off; off += (size_t)BCD * TCD * WEMBD;
    float* xg_c  = ws + off; off += (size_t)BCD * TCD * 4 * HD;
    float* cap_h = ws + off; off += (size_t)BCD * TCD * HD;
    float* c_lin = ws + off; off += (size_t)BCD * TCD * AD;
    float* v_lin = ws + off; off += (size_t)BD * TVD * AD;      // 4.19M
    float* wbar  = ws + off; off += (size_t)BD * TCD;
    float* cap_ha = ws + off; off += (size_t)BCD * HD;
    float* cap_hb = ws + off; off += (size_t)BCD * HD;
    float* cap_cst = ws + off; off += (size_t)BCD * HD;

    hipMemsetAsync(h_a, 0, (size_t)BD * HD * sizeof(float), stream);
    hipMemsetAsync(c_st, 0, (size_t)BD * HD * sizeof(float), stream);
    hipMemsetAsync(cap_ha, 0, (size_t)BCD * HD * sizeof(float), stream);
    hipMemsetAsync(cap_cst, 0, (size_t)BCD * HD * sizeof(float), stream);

    // caption path
    gemm_bias_kernel<<<dim3(WEMBD / 64, (BCD * TCD) / 64), 256, 0, stream>>>(
        video_caption, W_wemb, b_wemb, cap_x, BCD * TCD, WEMBD, GLOVED);
    gemm_bias_kernel<<<dim3((4 * HD) / 64, (BCD * TCD) / 64), 256, 0, stream>>>(
        cap_x, Wih_c, bih_c, xg_c, BCD * TCD, 4 * HD, WEMBD);
    for (int t = 0; t < TCD; t++) {
        const float* hin = (t & 1) ? cap_hb : cap_ha;
        float* hout = (t & 1) ? cap_ha : cap_hb;
        cap_step_kernel<<<32, 256, 0, stream>>>(xg_c, Whh_c, bhh_c, hin, hout, cap_cst, cap_h, t);
    }
    gemm_bias_kernel<<<dim3(AD / 64, (BCD * TCD) / 64), 256, 0, stream>>>(
        cap_h, W_sen, b_sen, c_lin, BCD * TCD, AD, HD);

    // video path
    gemm_bias_kernel<<<dim3(VEMBD / 64, (BD * TVD) / 64), 256, 0, stream>>>(
        video_fc, W_vemb, b_vemb, vid_x, BD * TVD, VEMBD, FCD);
    for (int t = 0; t < TVD; t++) {
        const float* hin = (t & 1) ? h_b : h_a;
        float* hout = (t & 1) ? h_a : h_b;
        vid_step_kernel<<<dim3(HD / 16, BD / 64), 512, 0, stream>>>(
            vid_x, Wih_v, Whh_v, bih_v, bhh_v, hin, hout, c_st, vid_h, t);
    }
    gemm_bias_kernel<<<dim3(AD / 64, (BD * TVD) / 64), 256, 0, stream>>>(
        vid_h, W_vid, b_vid, v_lin, BD * TVD, AD, HD);

    // attention + outputs
    attn_kernel<<<BD, 256, 0, stream>>>(v_lin, c_lin, W_att, b_att, cap_len, wbar);
    capftr_kernel<<<(BD * HD) / 256, 256, 0, stream>>>(wbar, cap_h, out2);
    vidmean_kernel<<<(BD * HD) / 256, 256, 0, stream>>>(vid_h, out1);
}

// Round 4
// 1183.637 us; speedup vs baseline: 4.3743x; 2.4843x over previous
//
#include <hip/hip_runtime.h>
#include <hip/hip_bf16.h>
#include <string.h>

#define FCD 2048
#define VEMBD 512
#define WEMBD 512
#define HD 512
#define AD 256
#define TVD 32
#define TCD 20
#define BCD 16
#define RPD 32
#define BD 512     // BCD*RPD
#define GLOVED 300

typedef __attribute__((ext_vector_type(8))) short short8v;
typedef __attribute__((ext_vector_type(4))) float f32x4;

__device__ __forceinline__ float sigf(float x) { return 1.0f / (1.0f + __expf(-x)); }
__device__ __forceinline__ float tanhfast(float x) {
    float e = __expf(2.0f * x);
    return 1.0f - 2.0f / (e + 1.0f);
}
__device__ __forceinline__ unsigned short f2bf(float x) {
    union { __hip_bfloat16 h; unsigned short u; } v;
    v.h = __float2bfloat16(x);
    return v.u;
}
__device__ __forceinline__ float b2f(unsigned short u) {
    union { unsigned int i; float f; } v;
    v.i = ((unsigned int)u) << 16;
    return v.f;
}

// ---------------------------------------------------------------------------
// fp32 -> bf16 elementwise convert (grid-stride, float4 in / ushort4 out)
// ---------------------------------------------------------------------------
__launch_bounds__(256)
__global__ void conv_f2b_kernel(const float* __restrict__ src,
                                unsigned short* __restrict__ dst, int n4) {
    for (int i = blockIdx.x * 256 + threadIdx.x; i < n4; i += gridDim.x * 256) {
        const float4 v = ((const float4*)src)[i];
        ushort4 o;
        o.x = f2bf(v.x); o.y = f2bf(v.y); o.z = f2bf(v.z); o.w = f2bf(v.w);
        ((ushort4*)dst)[i] = o;
    }
}

// ---------------------------------------------------------------------------
// Permuted+concatenated gate weights: Wcat[g'][0:512]=Wih[g], [512:1024]=Whh[g]
// g' = (hc>>4)*64 + q*16 + (hc&15), g = q*512 + hc. bf16 out.
// ---------------------------------------------------------------------------
__launch_bounds__(256)
__global__ void conv_wcat_perm_kernel(const float* __restrict__ Wih,
                                      const float* __restrict__ Whh,
                                      unsigned short* __restrict__ Wcat) {
    const int gp = blockIdx.x;                 // 0..2047
    const int q = (gp >> 4) & 3;
    const int hc = (gp >> 6) * 16 + (gp & 15);
    const long g = (long)(q * 512 + hc);
    for (int k = threadIdx.x; k < 512; k += 256) {
        Wcat[(long)gp * 1024 + k]       = f2bf(Wih[g * 512 + k]);
        Wcat[(long)gp * 1024 + 512 + k] = f2bf(Whh[g * 512 + k]);
    }
}

__launch_bounds__(256)
__global__ void conv_bsum_kernel(const float* __restrict__ bih,
                                 const float* __restrict__ bhh,
                                 float* __restrict__ bsum) {
    const int gp = blockIdx.x * 256 + threadIdx.x;
    if (gp < 2048) {
        const int q = (gp >> 4) & 3;
        const int hc = (gp >> 6) * 16 + (gp & 15);
        const int g = q * 512 + hc;
        bsum[gp] = bih[g] + bhh[g];
    }
}

// ---------------------------------------------------------------------------
// MFMA bf16 GEMM, 128x128 tile: C[M,N] = A[M,K] @ Bw[N,K]^T + bias[N]
// 256 threads = 4 waves (2x2 of 64x64), 4x4 frags of 16x16x32 each.
// AF32: A is fp32 in global, converted during staging. OBF: write C as bf16.
// M%128==0, N%128==0, K%32==0.
// ---------------------------------------------------------------------------
template<int AF32, int OBF>
__launch_bounds__(256)
__global__ void mfma_gemm128(const void* __restrict__ A,
                             const unsigned short* __restrict__ Bw,
                             const float* __restrict__ bias,
                             void* __restrict__ Cout,
                             int M, int N, int K)
{
    __shared__ unsigned short As[128][40];   // padded: 80B row stride (16B-aligned)
    __shared__ unsigned short Bs[128][40];
    const int n0 = blockIdx.x * 128;
    const int m0 = blockIdx.y * 128;
    const int tid = threadIdx.x;
    const int lane = tid & 63;
    const int wid = tid >> 6;
    const int wm = (wid >> 1) * 64;
    const int wn = (wid & 1) * 64;
    const int lrow = lane & 15;
    const int lko = (lane >> 4) * 8;   // k-offset (elem) of this lane's frag slice

    f32x4 acc[4][4] = {};

    for (int k0 = 0; k0 < K; k0 += 32) {
#pragma unroll
        for (int i = 0; i < 2; i++) {
            const int chunk = tid + i * 256;        // 0..511
            const int r = chunk >> 2;
            const int c8 = (chunk & 3) * 8;
            if (AF32) {
                const float* Af = (const float*)A + (long)(m0 + r) * K + k0 + c8;
                const float4 v0 = *(const float4*)Af;
                const float4 v1 = *(const float4*)(Af + 4);
                unsigned short* d = &As[r][c8];
                d[0] = f2bf(v0.x); d[1] = f2bf(v0.y); d[2] = f2bf(v0.z); d[3] = f2bf(v0.w);
                d[4] = f2bf(v1.x); d[5] = f2bf(v1.y); d[6] = f2bf(v1.z); d[7] = f2bf(v1.w);
            } else {
                *(short8v*)&As[r][c8] =
                    *(const short8v*)((const unsigned short*)A + (long)(m0 + r) * K + k0 + c8);
            }
            *(short8v*)&Bs[r][c8] =
                *(const short8v*)(Bw + (long)(n0 + r) * K + k0 + c8);
        }
        __syncthreads();
        short8v a[4], b[4];
#pragma unroll
        for (int mi = 0; mi < 4; mi++)
            a[mi] = *(const short8v*)&As[wm + mi * 16 + lrow][lko];
#pragma unroll
        for (int ni = 0; ni < 4; ni++)
            b[ni] = *(const short8v*)&Bs[wn + ni * 16 + lrow][lko];
#pragma unroll
        for (int mi = 0; mi < 4; mi++)
#pragma unroll
            for (int ni = 0; ni < 4; ni++)
                acc[mi][ni] = __builtin_amdgcn_mfma_f32_16x16x32_bf16(
                    a[mi], b[ni], acc[mi][ni], 0, 0, 0);
        __syncthreads();
    }

    const int rbase = (lane >> 4) * 4;
#pragma unroll
    for (int ni = 0; ni < 4; ni++) {
        const int col = n0 + wn + ni * 16 + lrow;
        const float bv = bias[col];
#pragma unroll
        for (int mi = 0; mi < 4; mi++) {
#pragma unroll
            for (int j = 0; j < 4; j++) {
                const long row = m0 + wm + mi * 16 + rbase + j;
                const float val = acc[mi][ni][j] + bv;
                if (OBF) ((unsigned short*)Cout)[row * N + col] = f2bf(val);
                else     ((float*)Cout)[row * N + col] = val;
            }
        }
    }
}

// ---------------------------------------------------------------------------
// Video LSTM step (bf16 MFMA): gates[b][g'] = [vid_x[b,t], h_in[b]] @ Wcat[g']^T
// + bsum[g'], then in-register cell update (gate layout makes q = frag index).
// 64 batch x 64 g' tiles, 256 threads = 4 waves (wave = 16 batch rows).
// ---------------------------------------------------------------------------
__launch_bounds__(256)
__global__ void vid_step_mfma(const unsigned short* __restrict__ vx,   // [B*TV][512] bf16
                              const unsigned short* __restrict__ h_in, // [B][512] bf16
                              const unsigned short* __restrict__ Wcat, // [2048][1024] bf16 g'
                              const float* __restrict__ bsum,          // [2048] g'
                              float* __restrict__ c_state,             // [B][512] f32
                              unsigned short* __restrict__ h_out,      // [B][512] bf16
                              unsigned short* __restrict__ vid_h,      // [B*TV][512] bf16
                              int t)
{
    __shared__ unsigned short Hs[64][40];
    __shared__ unsigned short Ws2[64][40];
    const int n0 = blockIdx.x * 64;   // g' base (32 blocks)
    const int b0 = blockIdx.y * 64;   // batch base (8 blocks)
    const int tid = threadIdx.x;
    const int lane = tid & 63;
    const int w = tid >> 6;
    const int lrow = lane & 15;
    const int lko = (lane >> 4) * 8;
    const int sr = tid >> 2;          // staging row 0..63
    const int sc8 = (tid & 3) * 8;

    f32x4 acc[4] = {};

    for (int k0 = 0; k0 < 1024; k0 += 32) {
        const unsigned short* asrc = (k0 < 512)
            ? (vx + ((long)(b0 + sr) * TVD + t) * 512 + k0 + sc8)
            : (h_in + (long)(b0 + sr) * 512 + (k0 - 512) + sc8);
        *(short8v*)&Hs[sr][sc8] = *(const short8v*)asrc;
        *(short8v*)&Ws2[sr][sc8] = *(const short8v*)(Wcat + (long)(n0 + sr) * 1024 + k0 + sc8);
        __syncthreads();
        const short8v a = *(const short8v*)&Hs[w * 16 + lrow][lko];
#pragma unroll
        for (int ni = 0; ni < 4; ni++) {
            const short8v b = *(const short8v*)&Ws2[ni * 16 + lrow][lko];
            acc[ni] = __builtin_amdgcn_mfma_f32_16x16x32_bf16(a, b, acc[ni], 0, 0, 0);
        }
        __syncthreads();
    }

    const int hc = (n0 >> 2) + lrow;         // n0/4 + lrow
    const int rbase = (lane >> 4) * 4;
    const float bs0 = bsum[n0 + lrow];
    const float bs1 = bsum[n0 + 16 + lrow];
    const float bs2 = bsum[n0 + 32 + lrow];
    const float bs3 = bsum[n0 + 48 + lrow];
#pragma unroll
    for (int j = 0; j < 4; j++) {
        const long b = b0 + w * 16 + rbase + j;
        const float gi = acc[0][j] + bs0;
        const float gf = acc[1][j] + bs1;
        const float gg = acc[2][j] + bs2;
        const float go = acc[3][j] + bs3;
        const float c_old = c_state[b * 512 + hc];
        const float ii = sigf(gi), ff = sigf(gf), g2 = tanhfast(gg), oo = sigf(go);
        const float c = ff * c_old + ii * g2;
        const float h = oo * tanhfast(c);
        c_state[b * 512 + hc] = c;
        h_out[b * 512 + hc] = f2bf(h);
        vid_h[(b * TVD + t) * 512 + hc] = f2bf(h);
    }
}

// ---------------------------------------------------------------------------
// Generic fp32 tiled GEMM (cap path only): C[M,N] = A[M,K] @ Bw[N,K]^T + bias
// ---------------------------------------------------------------------------
__launch_bounds__(256)
__global__ void gemm_bias_kernel(const float* __restrict__ A,
                                 const float* __restrict__ Bw,
                                 const float* __restrict__ bias,
                                 float* __restrict__ C,
                                 int M, int N, int K) {
    __shared__ float As[16][68];
    __shared__ float Bs[16][68];
    const int n0 = blockIdx.x * 64;
    const int m0 = blockIdx.y * 64;
    const int tid = threadIdx.x;
    const int tx = tid & 15;
    const int ty = tid >> 4;
    const int lrow = tid >> 2;
    const int lk4 = (tid & 3) * 4;

    float acc[4][4] = {};

    for (int k0 = 0; k0 < K; k0 += 16) {
        {
            const float* src = A + (long)(m0 + lrow) * K + k0 + lk4;
            float4 v;
            if (k0 + 16 <= K) v = *(const float4*)src;
            else {
                v.x = (k0 + lk4 + 0 < K) ? src[0] : 0.f;
                v.y = (k0 + lk4 + 1 < K) ? src[1] : 0.f;
                v.z = (k0 + lk4 + 2 < K) ? src[2] : 0.f;
                v.w = (k0 + lk4 + 3 < K) ? src[3] : 0.f;
            }
            As[lk4 + 0][lrow] = v.x; As[lk4 + 1][lrow] = v.y;
            As[lk4 + 2][lrow] = v.z; As[lk4 + 3][lrow] = v.w;
        }
        {
            const float* src = Bw + (long)(n0 + lrow) * K + k0 + lk4;
            float4 v;
            if (k0 + 16 <= K) v = *(const float4*)src;
            else {
                v.x = (k0 + lk4 + 0 < K) ? src[0] : 0.f;
                v.y = (k0 + lk4 + 1 < K) ? src[1] : 0.f;
                v.z = (k0 + lk4 + 2 < K) ? src[2] : 0.f;
                v.w = (k0 + lk4 + 3 < K) ? src[3] : 0.f;
            }
            Bs[lk4 + 0][lrow] = v.x; Bs[lk4 + 1][lrow] = v.y;
            Bs[lk4 + 2][lrow] = v.z; Bs[lk4 + 3][lrow] = v.w;
        }
        __syncthreads();
#pragma unroll
        for (int kk = 0; kk < 16; kk++) {
            const float4 av = *(const float4*)&As[kk][ty * 4];
            const float4 bv = *(const float4*)&Bs[kk][tx * 4];
            acc[0][0] += av.x * bv.x; acc[0][1] += av.x * bv.y; acc[0][2] += av.x * bv.z; acc[0][3] += av.x * bv.w;
            acc[1][0] += av.y * bv.x; acc[1][1] += av.y * bv.y; acc[1][2] += av.y * bv.z; acc[1][3] += av.y * bv.w;
            acc[2][0] += av.z * bv.x; acc[2][1] += av.z * bv.y; acc[2][2] += av.z * bv.z; acc[2][3] += av.z * bv.w;
            acc[3][0] += av.w * bv.x; acc[3][1] += av.w * bv.y; acc[3][2] += av.w * bv.z; acc[3][3] += av.w * bv.w;
        }
        __syncthreads();
    }

    const float b0v = bias[n0 + tx * 4 + 0];
    const float b1v = bias[n0 + tx * 4 + 1];
    const float b2v = bias[n0 + tx * 4 + 2];
    const float b3v = bias[n0 + tx * 4 + 3];
#pragma unroll
    for (int i = 0; i < 4; i++) {
        float* dst = C + (long)(m0 + ty * 4 + i) * N + n0 + tx * 4;
        dst[0] = acc[i][0] + b0v;
        dst[1] = acc[i][1] + b1v;
        dst[2] = acc[i][2] + b2v;
        dst[3] = acc[i][3] + b3v;
    }
}

// ---------------------------------------------------------------------------
// Caption LSTM step (fp32, small): 32 blocks x 256 threads.
// ---------------------------------------------------------------------------
__launch_bounds__(256)
__global__ void cap_step_kernel(const float* __restrict__ xg,
                                const float* __restrict__ Whh,
                                const float* __restrict__ bhh,
                                const float* __restrict__ h_in,
                                float* __restrict__ h_out,
                                float* __restrict__ c_state,
                                float* __restrict__ cap_h,
                                int t)
{
    __shared__ float Ws[64][68];
    __shared__ float Hsh[16][68];
    const int h0 = blockIdx.x * 16;
    const int tid = threadIdx.x;
    const int tx = tid & 15;
    const int ty = tid >> 4;
    const int lrow = tid >> 2;
    const int lq = tid & 3;

    float acc[4] = {};

    for (int k0 = 0; k0 < 512; k0 += 64) {
        {
            const int q = lrow >> 4;
            const int hcc = lrow & 15;
            const float* src = Whh + (long)(q * 512 + h0 + hcc) * 512 + k0 + lq * 16;
            const int col = hcc * 4 + q;
#pragma unroll
            for (int j = 0; j < 4; j++) {
                const float4 v = *(const float4*)(src + j * 4);
                Ws[lq * 16 + j * 4 + 0][col] = v.x;
                Ws[lq * 16 + j * 4 + 1][col] = v.y;
                Ws[lq * 16 + j * 4 + 2][col] = v.z;
                Ws[lq * 16 + j * 4 + 3][col] = v.w;
            }
        }
        {
            const int lb = tid >> 4;
            const int lk4 = (tid & 15) * 4;
            *(float4*)&Hsh[lb][lk4] = *(const float4*)(h_in + (long)lb * 512 + k0 + lk4);
        }
        __syncthreads();
#pragma unroll
        for (int kq = 0; kq < 16; kq++) {
            const float4 h4 = *(const float4*)&Hsh[ty][kq * 4];
            const float4 w0 = *(const float4*)&Ws[kq * 4 + 0][tx * 4];
            const float4 w1 = *(const float4*)&Ws[kq * 4 + 1][tx * 4];
            const float4 w2 = *(const float4*)&Ws[kq * 4 + 2][tx * 4];
            const float4 w3 = *(const float4*)&Ws[kq * 4 + 3][tx * 4];
            acc[0] += h4.x * w0.x + h4.y * w1.x + h4.z * w2.x + h4.w * w3.x;
            acc[1] += h4.x * w0.y + h4.y * w1.y + h4.z * w2.y + h4.w * w3.y;
            acc[2] += h4.x * w0.z + h4.y * w1.z + h4.z * w2.z + h4.w * w3.z;
            acc[3] += h4.x * w0.w + h4.y * w1.w + h4.z * w2.w + h4.w * w3.w;
        }
        __syncthreads();
    }

    const int hc = h0 + tx;
    const long xrow = (long)(ty * TCD + t) * 2048;
    const float gi = acc[0] + xg[xrow + hc]        + bhh[hc];
    const float gf = acc[1] + xg[xrow + 512 + hc]  + bhh[512 + hc];
    const float gg = acc[2] + xg[xrow + 1024 + hc] + bhh[1024 + hc];
    const float go = acc[3] + xg[xrow + 1536 + hc] + bhh[1536 + hc];
    const float c_old = c_state[(long)ty * 512 + hc];
    const float ii = sigf(gi), ff = sigf(gf), g2 = tanhfast(gg), oo = sigf(go);
    const float c = ff * c_old + ii * g2;
    const float h = oo * tanhfast(c);
    c_state[(long)ty * 512 + hc] = c;
    h_out[(long)ty * 512 + hc] = h;
    cap_h[(long)(ty * TCD + t) * 512 + hc] = h;
}

// ---------------------------------------------------------------------------
// Attention: one block per (bc, rp); scores -> masked softmax -> wbar mean_v.
// ---------------------------------------------------------------------------
__launch_bounds__(256)
__global__ void attn_kernel(const float* __restrict__ v_lin,
                            const float* __restrict__ c_lin,
                            const float* __restrict__ W_att,
                            const float* __restrict__ b_att,
                            const int* __restrict__ cap_len,
                            float* __restrict__ wbar)
{
    const int br = blockIdx.x;
    const int bc = br >> 5;
    const int tid = threadIdx.x;
    const int lane = tid & 63;
    const int wv = tid >> 6;
    __shared__ float cl[TCD][AD];
    __shared__ float vl[AD];
    __shared__ float sl[TVD][TCD];

    for (int tt = 0; tt < TCD; tt++)
        cl[tt][tid] = c_lin[(long)(bc * TCD + tt) * AD + tid];
    const float wa0 = W_att[lane];
    const float wa1 = W_att[64 + lane];
    const float wa2 = W_att[128 + lane];
    const float wa3 = W_att[192 + lane];
    const float batt = b_att[0];
    __syncthreads();

    for (int v = 0; v < TVD; v++) {
        vl[tid] = v_lin[((long)br * TVD + v) * AD + tid];
        __syncthreads();
        const float v0 = vl[lane], v1 = vl[64 + lane], v2 = vl[128 + lane], v3 = vl[192 + lane];
#pragma unroll
        for (int dt = 0; dt < 5; dt++) {
            const int t = wv * 5 + dt;
            float s = tanhfast(v0 + cl[t][lane]) * wa0
                    + tanhfast(v1 + cl[t][64 + lane]) * wa1
                    + tanhfast(v2 + cl[t][128 + lane]) * wa2
                    + tanhfast(v3 + cl[t][192 + lane]) * wa3;
            for (int off = 32; off > 0; off >>= 1) s += __shfl_down(s, off, 64);
            if (lane == 0) sl[v][t] = s + batt;
        }
        __syncthreads();
    }

    int L = cap_len[bc];
    if (L < 1) L = 1;
    if (tid < TVD) {
        const int v = tid;
        float m = -1e30f;
        for (int t = 0; t < TCD; t++)
            if (t < L) m = fmaxf(m, sl[v][t]);
        float sum = 0.f;
        for (int t = 0; t < TCD; t++)
            if (t < L) sum += __expf(sl[v][t] - m);
        const float inv = 1.f / sum;
        for (int t = 0; t < TCD; t++)
            sl[v][t] = (t < L) ? __expf(sl[v][t] - m) * inv : 0.f;
    }
    __syncthreads();
    if (tid < TCD) {
        float s = 0.f;
        for (int v = 0; v < TVD; v++) s += sl[v][tid];
        wbar[(long)br * TCD + tid] = s * (1.0f / TVD);
    }
}

__launch_bounds__(256)
__global__ void capftr_kernel(const float* __restrict__ wbar,
                              const float* __restrict__ cap_h,
                              float* __restrict__ out2)
{
    const int idx = blockIdx.x * 256 + threadIdx.x;
    const int h = idx & 511;
    const int br = idx >> 9;
    const int bc = br >> 5;
    float s = 0.f;
#pragma unroll
    for (int t = 0; t < TCD; t++)
        s += wbar[br * TCD + t] * cap_h[(long)(bc * TCD + t) * HD + h];
    out2[idx] = s;
}

// vid_mean from bf16 vid_h: thread = (b, 8-h chunk)
__launch_bounds__(256)
__global__ void vidmean_bf_kernel(const unsigned short* __restrict__ vid_h,
                                  float* __restrict__ out1)
{
    const int idx = blockIdx.x * 256 + threadIdx.x;   // 0..32767
    const int b = idx >> 6;
    const int h8 = (idx & 63) * 8;
    float s[8] = {};
    for (int t = 0; t < TVD; t++) {
        const short8v v = *(const short8v*)(vid_h + ((long)b * TVD + t) * 512 + h8);
#pragma unroll
        for (int j = 0; j < 8; j++) s[j] += b2f((unsigned short)v[j]);
    }
#pragma unroll
    for (int j = 0; j < 8; j++)
        out1[(long)b * 512 + h8 + j] = s[j] * (1.0f / TVD);
}

extern "C" void kernel_launch(void* const* d_in, const int* in_sizes, int n_in,
                              void* d_out, int out_size, void* d_ws, size_t ws_size,
                              hipStream_t stream) {
    const float* video_fc      = (const float*)d_in[0];
    const float* video_caption = (const float*)d_in[1];
    const int*   cap_len       = (const int*)d_in[2];
    const float* W_vemb = (const float*)d_in[3];
    const float* b_vemb = (const float*)d_in[4];
    const float* W_wemb = (const float*)d_in[5];
    const float* b_wemb = (const float*)d_in[6];
    const float* Wih_v  = (const float*)d_in[7];
    const float* Whh_v  = (const float*)d_in[8];
    const float* bih_v  = (const float*)d_in[9];
    const float* bhh_v  = (const float*)d_in[10];
    const float* Wih_c  = (const float*)d_in[11];
    const float* Whh_c  = (const float*)d_in[12];
    const float* bih_c  = (const float*)d_in[13];
    const float* bhh_c  = (const float*)d_in[14];
    const float* W_vid  = (const float*)d_in[15];
    const float* b_vid  = (const float*)d_in[16];
    const float* W_sen  = (const float*)d_in[17];
    const float* b_sen  = (const float*)d_in[18];
    const float* W_att  = (const float*)d_in[19];
    const float* b_att  = (const float*)d_in[20];

    float* out1 = (float*)d_out;            // vid_mean
    float* out2 = out1 + BD * HD;           // cap_ftr_mean

    float* ws = (float*)d_ws;
    size_t off = 0;
    auto alloc = [&](size_t nfloats) {
        float* p = ws + off;
        off += (nfloats + 63) & ~(size_t)63;
        return p;
    };
    unsigned short* vidx_bf = (unsigned short*)alloc((size_t)BD * TVD * VEMBD / 2);
    unsigned short* vidh_bf = (unsigned short*)alloc((size_t)BD * TVD * HD / 2);
    unsigned short* h_bf_a  = (unsigned short*)alloc((size_t)BD * HD / 2);
    unsigned short* h_bf_b  = (unsigned short*)alloc((size_t)BD * HD / 2);
    float* c_st    = alloc((size_t)BD * HD);
    float* v_lin   = alloc((size_t)BD * TVD * AD);
    unsigned short* Wvemb_bf = (unsigned short*)alloc((size_t)VEMBD * FCD / 2);
    unsigned short* Wvid_bf  = (unsigned short*)alloc((size_t)AD * HD / 2);
    unsigned short* Wcat_bf  = (unsigned short*)alloc((size_t)2048 * 1024 / 2);
    float* bsum    = alloc(2048);
    float* cap_x   = alloc((size_t)BCD * TCD * WEMBD);
    float* xg_c    = alloc((size_t)BCD * TCD * 4 * HD);
    float* cap_h   = alloc((size_t)BCD * TCD * HD);
    float* c_lin   = alloc((size_t)BCD * TCD * AD);
    float* wbar    = alloc((size_t)BD * TCD);
    float* cap_ha  = alloc((size_t)BCD * HD);
    float* cap_hb  = alloc((size_t)BCD * HD);
    float* cap_cst = alloc((size_t)BCD * HD);

    hipMemsetAsync(h_bf_a, 0, (size_t)BD * HD * sizeof(unsigned short), stream);
    hipMemsetAsync(c_st, 0, (size_t)BD * HD * sizeof(float), stream);
    hipMemsetAsync(cap_ha, 0, (size_t)BCD * HD * sizeof(float), stream);
    hipMemsetAsync(cap_cst, 0, (size_t)BCD * HD * sizeof(float), stream);

    // weight conversions
    conv_f2b_kernel<<<512, 256, 0, stream>>>(W_vemb, Wvemb_bf, VEMBD * FCD / 4);
    conv_f2b_kernel<<<128, 256, 0, stream>>>(W_vid, Wvid_bf, AD * HD / 4);
    conv_wcat_perm_kernel<<<2048, 256, 0, stream>>>(Wih_v, Whh_v, Wcat_bf);
    conv_bsum_kernel<<<8, 256, 0, stream>>>(bih_v, bhh_v, bsum);

    // caption path (fp32)
    gemm_bias_kernel<<<dim3(WEMBD / 64, (BCD * TCD) / 64), 256, 0, stream>>>(
        video_caption, W_wemb, b_wemb, cap_x, BCD * TCD, WEMBD, GLOVED);
    gemm_bias_kernel<<<dim3((4 * HD) / 64, (BCD * TCD) / 64), 256, 0, stream>>>(
        cap_x, Wih_c, bih_c, xg_c, BCD * TCD, 4 * HD, WEMBD);
    for (int t = 0; t < TCD; t++) {
        const float* hin = (t & 1) ? cap_hb : cap_ha;
        float* hout = (t & 1) ? cap_ha : cap_hb;
        cap_step_kernel<<<32, 256, 0, stream>>>(xg_c, Whh_c, bhh_c, hin, hout, cap_cst, cap_h, t);
    }
    gemm_bias_kernel<<<dim3(AD / 64, (BCD * TCD) / 64), 256, 0, stream>>>(
        cap_h, W_sen, b_sen, c_lin, BCD * TCD, AD, HD);

    // video path (bf16 MFMA)
    mfma_gemm128<1, 1><<<dim3(VEMBD / 128, (BD * TVD) / 128), 256, 0, stream>>>(
        video_fc, Wvemb_bf, b_vemb, vidx_bf, BD * TVD, VEMBD, FCD);
    for (int t = 0; t < TVD; t++) {
        const unsigned short* hin = (t & 1) ? h_bf_b : h_bf_a;
        unsigned short* hout = (t & 1) ? h_bf_a : h_bf_b;
        vid_step_mfma<<<dim3(2048 / 64, BD / 64), 256, 0, stream>>>(
            vidx_bf, hin, Wcat_bf, bsum, c_st, hout, vidh_bf, t);
    }
    mfma_gemm128<0, 0><<<dim3(AD / 128, (BD * TVD) / 128), 256, 0, stream>>>(
        vidh_bf, Wvid_bf, b_vid, v_lin, BD * TVD, AD, HD);

    // attention + outputs
    attn_kernel<<<BD, 256, 0, stream>>>(v_lin, c_lin, W_att, b_att, cap_len, wbar);
    capftr_kernel<<<(BD * HD) / 256, 256, 0, stream>>>(wbar, cap_h, out2);
    vidmean_bf_kernel<<<(BD * HD / 8) / 256, 256, 0, stream>>>(vidh_bf, out1);
}